// Round 2
// baseline (275.735 us; speedup 1.0000x reference)
//
#include <hip/hip_runtime.h>
#include <hip/hip_bf16.h>

typedef __attribute__((ext_vector_type(8))) short bf16x8;
typedef __attribute__((ext_vector_type(4))) float f32x4;

// Problem dims (fixed by the reference setup_inputs)
#define B   4
#define CIN 128
#define COUT 256
#define H   256
#define W   256
#define HW  (H * W)          // 65536

__device__ __forceinline__ unsigned short f2bf(float f) {
  unsigned int u = __builtin_bit_cast(unsigned int, f);
  u += 0x7fff + ((u >> 16) & 1);   // round-to-nearest-even
  return (unsigned short)(u >> 16);
}

// ---------------------------------------------------------------------------
// Kernel 0: convert w_pw (COUT x CIN f32) -> bf16 row-major
// ---------------------------------------------------------------------------
__global__ void cvt_wpw(const float* __restrict__ w, unsigned short* __restrict__ o) {
  int i = blockIdx.x * 256 + threadIdx.x;
  if (i < COUT * CIN) o[i] = f2bf(w[i]);
}

// ---------------------------------------------------------------------------
// Kernel 1 (v2): depthwise 3x3, pad 1. Writes y as bf16 in layout
//   y[(b*16 + ciBlk) * HW + hw] : 8 contiguous bf16 (ci = ciBlk*8 + 0..7)
//
// v2 changes vs v1:
//  - each block computes 8 output rows (reads 10) -> x HBM refetch 3.0 -> 1.25
//  - thread owns 4 consecutive px -> one aligned f32x4 load + 2 halo scalars
//    per (ci,dh) instead of 3 bounds-checked scalar loads
//  - 72 dw weights hoisted to registers once (was LDS reads in inner loop)
// Grid: b(4) * hChunk(32: 8 rows) * wTile(4: 64 px) = 512 blocks, 256 thr
// Thread t: ciBlk = t>>4 (8 ci each), pxg = t&15 (4 px each).
// ---------------------------------------------------------------------------
__global__ __launch_bounds__(256) void dw_kernel(const float* __restrict__ x,
                                                 const float* __restrict__ wdw,
                                                 unsigned short* __restrict__ y) {
  int blk = blockIdx.x;
  int wt = blk & 3;
  int hc = (blk >> 2) & 31;
  int b  = blk >> 7;

  __shared__ float wl[CIN * 9];
  for (int i = threadIdx.x; i < CIN * 9; i += 256) wl[i] = wdw[i];
  __syncthreads();

  int t = threadIdx.x;
  int ciBlk = t >> 4;          // 0..15
  int pxg   = t & 15;          // 0..15
  int ciBase = ciBlk * 8;
  int w0 = wt * 64 + pxg * 4;  // 4 consecutive px, 16B-aligned
  int hBase = hc * 8;

  // Hoist this thread's 8 channels x 9 weights into registers (all static idx)
  float wr[8][9];
#pragma unroll
  for (int ci = 0; ci < 8; ++ci)
#pragma unroll
    for (int k = 0; k < 9; ++k) wr[ci][k] = wl[(ciBase + ci) * 9 + k];

  const float* xb = x + (size_t)b * CIN * HW;

  for (int r = 0; r < 8; ++r) {
    int h = hBase + r;
    float acc[8][4];
#pragma unroll
    for (int i = 0; i < 8; ++i)
#pragma unroll
      for (int j = 0; j < 4; ++j) acc[i][j] = 0.f;

#pragma unroll
    for (int ci = 0; ci < 8; ++ci) {
      const float* xc = xb + (size_t)(ciBase + ci) * HW;
#pragma unroll
      for (int dh = 0; dh < 3; ++dh) {
        int hh = h + dh - 1;
        if (hh < 0 || hh >= H) continue;        // wave-uniform branch
        const float* xr = xc + hh * W;
        f32x4 v = *(const f32x4*)(xr + w0);
        float xm = (w0 > 0)     ? xr[w0 - 1] : 0.f;   // L1-hit halo
        float xp = (w0 + 4 < W) ? xr[w0 + 4] : 0.f;
        float ka = wr[ci][dh * 3 + 0];
        float kb = wr[ci][dh * 3 + 1];
        float kc = wr[ci][dh * 3 + 2];
        acc[ci][0] += xm   * ka + v[0] * kb + v[1] * kc;
        acc[ci][1] += v[0] * ka + v[1] * kb + v[2] * kc;
        acc[ci][2] += v[1] * ka + v[2] * kb + v[3] * kc;
        acc[ci][3] += v[2] * ka + v[3] * kb + xp   * kc;
      }
    }

    size_t rowbase = ((size_t)(b * 16 + ciBlk) * HW + h * W) * 8;
#pragma unroll
    for (int j = 0; j < 4; ++j) {
      bf16x8 vv;
#pragma unroll
      for (int i = 0; i < 8; ++i) vv[i] = (short)f2bf(acc[i][j]);
      *(bf16x8*)(y + rowbase + (size_t)(w0 + j) * 8) = vv;
    }
  }
}

// ---------------------------------------------------------------------------
// Kernel 2: pointwise 1x1 as GEMM via MFMA 16x16x32 bf16. (unchanged from R0)
// out[b, co, hw] = sum_ci wpw[co, ci] * y[b, ci, hw]
// Block = 4 waves; block tile = 256co x 64px. Wave w: co in [w*64, w*64+64).
// ---------------------------------------------------------------------------
__global__ __launch_bounds__(256) void pw_kernel(const unsigned short* __restrict__ y,
                                                 const unsigned short* __restrict__ wb,
                                                 float* __restrict__ out) {
  int blk = blockIdx.x;               // 4096
  int b = blk >> 10;
  int hwBase = (blk & 1023) * 64;
  int wave = threadIdx.x >> 6;
  int l    = threadIdx.x & 63;
  int l15 = l & 15, lg = l >> 4;
  int coBase = wave * 64;

  bf16x8 A[4][4];
#pragma unroll
  for (int m = 0; m < 4; ++m)
#pragma unroll
    for (int kk = 0; kk < 4; ++kk) {
      int co = coBase + m * 16 + l15;
      int ci = kk * 32 + lg * 8;
      A[m][kk] = *(const bf16x8*)(wb + co * CIN + ci);
    }

  f32x4 acc[4][4];
#pragma unroll
  for (int m = 0; m < 4; ++m)
#pragma unroll
    for (int n = 0; n < 4; ++n) acc[m][n] = (f32x4){0.f, 0.f, 0.f, 0.f};

  const unsigned short* yb = y + (size_t)b * 16 * HW * 8;
#pragma unroll
  for (int n = 0; n < 4; ++n) {
    bf16x8 Bf[4];
#pragma unroll
    for (int kk = 0; kk < 4; ++kk) {
      int ciBlk = kk * 4 + lg;
      int hw = hwBase + n * 16 + l15;
      Bf[kk] = *(const bf16x8*)(yb + ((size_t)ciBlk * HW + hw) * 8);
    }
#pragma unroll
    for (int m = 0; m < 4; ++m)
#pragma unroll
      for (int kk = 0; kk < 4; ++kk)
        acc[m][n] = __builtin_amdgcn_mfma_f32_16x16x32_bf16(A[m][kk], Bf[kk], acc[m][n], 0, 0, 0);
  }

  float* ob = out + (size_t)b * COUT * HW;
#pragma unroll
  for (int m = 0; m < 4; ++m)
#pragma unroll
    for (int n = 0; n < 4; ++n)
#pragma unroll
      for (int r = 0; r < 4; ++r) {
        int co = coBase + m * 16 + lg * 4 + r;
        int hw = hwBase + n * 16 + l15;
        ob[(size_t)co * HW + hw] = acc[m][n][r];
      }
}

extern "C" void kernel_launch(void* const* d_in, const int* in_sizes, int n_in,
                              void* d_out, int out_size, void* d_ws, size_t ws_size,
                              hipStream_t stream) {
  const float* x   = (const float*)d_in[0];
  const float* wdw = (const float*)d_in[1];
  const float* wpw = (const float*)d_in[2];
  float* out = (float*)d_out;

  // ws layout: y bf16 [B*16][HW][8] = 67,108,864 B, then wpw bf16 65,536 B
  unsigned short* y  = (unsigned short*)d_ws;
  unsigned short* wb = y + (size_t)B * CIN * HW;   // 33,554,432 elems

  cvt_wpw<<<(COUT * CIN + 255) / 256, 256, 0, stream>>>(wpw, wb);
  dw_kernel<<<B * 32 * 4, 256, 0, stream>>>(x, wdw, y);
  pw_kernel<<<B * (HW / 64), 256, 0, stream>>>(y, wb, out);
}

// Round 3
// 142.000 us; speedup vs baseline: 1.9418x; 1.9418x over previous
//
#include <hip/hip_runtime.h>
#include <hip/hip_bf16.h>

typedef __attribute__((ext_vector_type(8))) short bf16x8;
typedef __attribute__((ext_vector_type(4))) float f32x4;

// Problem dims (fixed by the reference setup_inputs)
#define B   4
#define CIN 128
#define COUT 256
#define H   256
#define W   256
#define HW  (H * W)          // 65536

__device__ __forceinline__ unsigned short f2bf(float f) {
  unsigned int u = __builtin_bit_cast(unsigned int, f);
  u += 0x7fff + ((u >> 16) & 1);   // round-to-nearest-even
  return (unsigned short)(u >> 16);
}

__device__ __forceinline__ void gload_lds16(const void* g, void* l) {
  __builtin_amdgcn_global_load_lds((const __attribute__((address_space(1))) void*)g,
                                   (__attribute__((address_space(3))) void*)l, 16, 0, 0);
}

// ---------------------------------------------------------------------------
// Kernel 0: convert w_pw (COUT x CIN f32) -> bf16 row-major
// ---------------------------------------------------------------------------
__global__ void cvt_wpw(const float* __restrict__ w, unsigned short* __restrict__ o) {
  int i = blockIdx.x * 256 + threadIdx.x;
  if (i < COUT * CIN) o[i] = f2bf(w[i]);
}

// ---------------------------------------------------------------------------
// Kernel 1 (v3): depthwise 3x3 pad 1 -> y bf16 [b*16+ciBlk][hw][8ci]
// Reuse strategy: rolling 3-row REGISTER window per thread (no L2 reliance).
// Grid 2048 = b(4) x cg(8:16ci) x hc(32:8 rows) x wt(2:128px); 256 thr.
// Thread: c = t>>4 (ci = cg*16+c), pxg = t&15 (8 px). ~70 VGPR -> high occ.
// Transpose for the [8ci] interleave via small double-buffered LDS.
// ---------------------------------------------------------------------------
struct Row { float L; f32x4 a; f32x4 b; float R; };

__device__ __forceinline__ float rget(const Row& r, int j) {
  // j in [-1, 8]; compile-time after unroll
  return (j < 0) ? r.L : (j < 4) ? r.a[j & 3] : (j < 8) ? r.b[j & 3] : r.R;
}

__device__ __forceinline__ Row load_row(const float* xr, int px0, bool pL, bool pR) {
  Row r;
  r.a = *(const f32x4*)(xr + px0);
  r.b = *(const f32x4*)(xr + px0 + 4);
  r.L = pL ? xr[px0 - 1] : 0.f;
  r.R = pR ? xr[px0 + 8] : 0.f;
  return r;
}

__device__ __forceinline__ Row zero_row() {
  Row r; r.L = r.R = 0.f;
  r.a = (f32x4){0.f, 0.f, 0.f, 0.f};
  r.b = (f32x4){0.f, 0.f, 0.f, 0.f};
  return r;
}

__global__ __launch_bounds__(256) void dw_kernel(const float* __restrict__ x,
                                                 const float* __restrict__ wdw,
                                                 unsigned short* __restrict__ y) {
  int blk = blockIdx.x;
  int wt = blk & 1;
  int hc = (blk >> 1) & 31;
  int cg = (blk >> 6) & 7;
  int b  = blk >> 9;

  int t = threadIdx.x;
  int c   = t >> 4;            // 0..15
  int pxg = t & 15;            // 0..15, 8 px each
  int ci  = cg * 16 + c;
  int px0 = wt * 128 + pxg * 8;
  int hBase = hc * 8;

  float wr[9];
#pragma unroll
  for (int k = 0; k < 9; ++k) wr[k] = wdw[ci * 9 + k];

  const float* xc = x + (size_t)(b * CIN + ci) * HW;
  bool pL = px0 > 0;
  bool pR = px0 + 8 < W;

  __shared__ __align__(16) unsigned short lt[2][16][136];   // 8.7 KB, dbuf

  Row rA = (hBase > 0) ? load_row(xc + (hBase - 1) * W, px0, pL, pR) : zero_row();
  Row rB = load_row(xc + hBase * W, px0, pL, pR);

#pragma unroll
  for (int r = 0; r < 8; ++r) {
    int h = hBase + r;
    Row rC = (h + 1 < H) ? load_row(xc + (h + 1) * W, px0, pL, pR) : zero_row();

    bf16x8 v;
#pragma unroll
    for (int j = 0; j < 8; ++j) {
      float acc =
        rget(rA, j - 1) * wr[0] + rget(rA, j) * wr[1] + rget(rA, j + 1) * wr[2] +
        rget(rB, j - 1) * wr[3] + rget(rB, j) * wr[4] + rget(rB, j + 1) * wr[5] +
        rget(rC, j - 1) * wr[6] + rget(rC, j) * wr[7] + rget(rC, j + 1) * wr[8];
      v[j] = (short)f2bf(acc);
    }
    int buf = r & 1;
    *(bf16x8*)&lt[buf][c][pxg * 8] = v;     // 16B, bank-balanced

    __syncthreads();

    // transpose-out: thread -> (cb = t>>7, px = t&127); 8 u16 reads (2-way free)
    int cb = t >> 7;
    int px = t & 127;
    const unsigned short* lp = &lt[buf][cb * 8][px];
    unsigned short s0 = lp[0 * 136], s1 = lp[1 * 136], s2 = lp[2 * 136], s3 = lp[3 * 136];
    unsigned short s4 = lp[4 * 136], s5 = lp[5 * 136], s6 = lp[6 * 136], s7 = lp[7 * 136];
    uint4 vv;
    vv.x = (unsigned)s0 | ((unsigned)s1 << 16);
    vv.y = (unsigned)s2 | ((unsigned)s3 << 16);
    vv.z = (unsigned)s4 | ((unsigned)s5 << 16);
    vv.w = (unsigned)s6 | ((unsigned)s7 << 16);
    size_t dst = ((size_t)(b * 16 + cg * 2 + cb) * HW + h * W + wt * 128 + px) * 8;
    *(uint4*)(y + dst) = vv;                // 64 lanes x 16B = 1KB contiguous

    rA = rB; rB = rC;
    // no second barrier: buf alternates; barrier at r+1 separates reads(r) from writes(r+2)
  }
}

// ---------------------------------------------------------------------------
// Kernel 2 (v2): pointwise 1x1 GEMM via MFMA 16x16x32 bf16, y tile staged to
// LDS with async global_load_lds (one vmcnt(0)+barrier per block; B-frags are
// ds_read_b128 from LDS instead of per-n-iter HBM loads).
// Block = 4 waves; tile = 256co x 64px. Wave w: co in [w*64, w*64+64).
// ---------------------------------------------------------------------------
__global__ __launch_bounds__(256) void pw_kernel(const unsigned short* __restrict__ y,
                                                 const unsigned short* __restrict__ wb,
                                                 float* __restrict__ out) {
  int blk = blockIdx.x;               // 4096
  int b = blk >> 10;
  int hwBase = (blk & 1023) * 64;
  int wave = threadIdx.x >> 6;
  int l    = threadIdx.x & 63;
  int l15 = l & 15, lg = l >> 4;
  int coBase = wave * 64;

  __shared__ __align__(16) unsigned short ytile[16 * 64 * 8];   // 16 KB

  const unsigned short* yb = y + (size_t)b * 16 * HW * 8;

  // async stage: 4 passes; wave stages ciBlk = p*4+wave (64 px x 8ci = 1KB/instr)
#pragma unroll
  for (int p = 0; p < 4; ++p) {
    int cb = p * 4 + wave;
    gload_lds16(yb + ((size_t)cb * HW + hwBase + l) * 8,
                &ytile[(size_t)cb * 64 * 8]);   // wave-uniform LDS base + lane*16B
  }

  bf16x8 A[4][4];
#pragma unroll
  for (int m = 0; m < 4; ++m)
#pragma unroll
    for (int kk = 0; kk < 4; ++kk) {
      int co = coBase + m * 16 + l15;
      int ci = kk * 32 + lg * 8;
      A[m][kk] = *(const bf16x8*)(wb + co * CIN + ci);
    }

  asm volatile("s_waitcnt vmcnt(0)" ::: "memory");
  __syncthreads();

  f32x4 acc[4][4];
#pragma unroll
  for (int m = 0; m < 4; ++m)
#pragma unroll
    for (int n = 0; n < 4; ++n) acc[m][n] = (f32x4){0.f, 0.f, 0.f, 0.f};

#pragma unroll
  for (int n = 0; n < 4; ++n) {
    bf16x8 Bf[4];
#pragma unroll
    for (int kk = 0; kk < 4; ++kk)
      Bf[kk] = *(const bf16x8*)&ytile[(size_t)((kk * 4 + lg) * 64 + n * 16 + l15) * 8];
#pragma unroll
    for (int m = 0; m < 4; ++m)
#pragma unroll
      for (int kk = 0; kk < 4; ++kk)
        acc[m][n] = __builtin_amdgcn_mfma_f32_16x16x32_bf16(A[m][kk], Bf[kk], acc[m][n], 0, 0, 0);
  }

  float* ob = out + (size_t)b * COUT * HW;
#pragma unroll
  for (int m = 0; m < 4; ++m)
#pragma unroll
    for (int n = 0; n < 4; ++n)
#pragma unroll
      for (int r = 0; r < 4; ++r) {
        int co = coBase + m * 16 + lg * 4 + r;
        int hw = hwBase + n * 16 + l15;
        ob[(size_t)co * HW + hw] = acc[m][n][r];
      }
}

extern "C" void kernel_launch(void* const* d_in, const int* in_sizes, int n_in,
                              void* d_out, int out_size, void* d_ws, size_t ws_size,
                              hipStream_t stream) {
  const float* x   = (const float*)d_in[0];
  const float* wdw = (const float*)d_in[1];
  const float* wpw = (const float*)d_in[2];
  float* out = (float*)d_out;

  // ws layout: y bf16 [B*16][HW][8] = 67,108,864 B, then wpw bf16 65,536 B
  unsigned short* y  = (unsigned short*)d_ws;
  unsigned short* wb = y + (size_t)B * CIN * HW;   // 33,554,432 elems

  cvt_wpw<<<(COUT * CIN + 255) / 256, 256, 0, stream>>>(wpw, wb);
  dw_kernel<<<2048, 256, 0, stream>>>(x, wdw, y);
  pw_kernel<<<B * (HW / 64), 256, 0, stream>>>(y, wb, out);
}

// Round 4
// 126.774 us; speedup vs baseline: 2.1750x; 1.1201x over previous
//
#include <hip/hip_runtime.h>
#include <hip/hip_bf16.h>

typedef __attribute__((ext_vector_type(8))) short bf16x8;
typedef __attribute__((ext_vector_type(4))) float f32x4;

#define B   4
#define CIN 128
#define COUT 256
#define H   256
#define W   256
#define HW  (H * W)          // 65536

__device__ __forceinline__ unsigned short f2bf(float f) {
  unsigned int u = __builtin_bit_cast(unsigned int, f);
  u += 0x7fff + ((u >> 16) & 1);   // round-to-nearest-even
  return (unsigned short)(u >> 16);
}

// ---------------------------------------------------------------------------
// Kernel 0: convert w_pw (COUT x CIN f32) -> bf16 row-major
// ---------------------------------------------------------------------------
__global__ void cvt_wpw(const float* __restrict__ w, unsigned short* __restrict__ o) {
  int i = blockIdx.x * 256 + threadIdx.x;
  if (i < COUT * CIN) o[i] = f2bf(w[i]);
}

// ---------------------------------------------------------------------------
// Fused depthwise3x3 + pointwise GEMM. One block = one output row h.
// Phase 1 (dw): 512 thr; thread = (ci-pair, 8px). Writes y_row[16cb][256px][8ci]
//   bf16 to LDS via u32 stores, XOR-swizzled (phys = La ^ ((La>>3)&0x70)):
//   bank = 4*((j ^ pxg)&7) + (c&3) -> 16 banks/wave = 4-way (1.58x, ok).
// Phase 2 (pw): 8 waves, wave tile 64co x 128px, MFMA 16x16x32 bf16, K=128.
//   B-frag = ds_read_b128 at same XOR -> 16 distinct granules -> 2-way free.
// XCD swizzle: vbid = (bid&7)*128 + bid>>3 -> each XCD owns 128 consecutive
//   rows; co-resident neighbors share h-halo rows in L2 concurrently.
// ---------------------------------------------------------------------------
struct Row { float L; f32x4 a; f32x4 b; float R; };

__device__ __forceinline__ float rget(const Row& r, int j) {
  return (j < 0) ? r.L : (j < 4) ? r.a[j & 3] : (j < 8) ? r.b[j & 3] : r.R;
}

__device__ __forceinline__ Row load_row(const float* xr, int px0, bool pL, bool pR) {
  Row r;
  r.a = *(const f32x4*)(xr + px0);
  r.b = *(const f32x4*)(xr + px0 + 4);
  r.L = pL ? xr[px0 - 1] : 0.f;
  r.R = pR ? xr[px0 + 8] : 0.f;
  return r;
}

__device__ __forceinline__ Row zero_row() {
  Row r; r.L = r.R = 0.f;
  r.a = (f32x4){0.f, 0.f, 0.f, 0.f};
  r.b = (f32x4){0.f, 0.f, 0.f, 0.f};
  return r;
}

__device__ __forceinline__ unsigned swz(unsigned La) {
  return La ^ ((La >> 3) & 0x70);
}

__global__ __launch_bounds__(512, 2) void fused_kernel(
    const float* __restrict__ x, const float* __restrict__ wdw,
    const unsigned short* __restrict__ wb, float* __restrict__ out)
{
  int bid = blockIdx.x;
  int vbid = (bid & 7) * 128 + (bid >> 3);   // XCD-contiguous rows
  int b = vbid >> 8;
  int h = vbid & 255;

  int t = threadIdx.x;
  int c   = t >> 5;            // 0..15  (ci-pair selector)
  int pxg = t & 31;            // 0..31  (8 px each)
  int px0 = pxg * 8;
  bool pL = px0 > 0, pR = px0 + 8 < W;

  __shared__ __align__(16) char yrow[16 * 256 * 16];   // 64 KB

  const float* xb = x + (size_t)b * CIN * HW;

  // ---------------- depthwise phase ----------------
#pragma unroll
  for (int q = 0; q < 4; ++q) {
    int ci0 = q * 32 + c * 2;            // even; pair = (ci0, ci0+1)
    const float* wp0 = wdw + ci0 * 9;
    float w0[9], w1[9];
#pragma unroll
    for (int k = 0; k < 9; ++k) { w0[k] = wp0[k]; w1[k] = wp0[9 + k]; }

    const float* xc0 = xb + (size_t)ci0 * HW;
    const float* xc1 = xc0 + HW;
    Row A0 = (h > 0)     ? load_row(xc0 + (size_t)(h - 1) * W, px0, pL, pR) : zero_row();
    Row B0 =               load_row(xc0 + (size_t)h * W,       px0, pL, pR);
    Row C0 = (h < H - 1) ? load_row(xc0 + (size_t)(h + 1) * W, px0, pL, pR) : zero_row();
    Row A1 = (h > 0)     ? load_row(xc1 + (size_t)(h - 1) * W, px0, pL, pR) : zero_row();
    Row B1 =               load_row(xc1 + (size_t)h * W,       px0, pL, pR);
    Row C1 = (h < H - 1) ? load_row(xc1 + (size_t)(h + 1) * W, px0, pL, pR) : zero_row();

    int cb = q * 4 + (c >> 2);           // ci0>>3
    int ep = c & 3;                      // (ci0&7)>>1
#pragma unroll
    for (int j = 0; j < 8; ++j) {
      float a0 =
        rget(A0, j-1)*w0[0] + rget(A0, j)*w0[1] + rget(A0, j+1)*w0[2] +
        rget(B0, j-1)*w0[3] + rget(B0, j)*w0[4] + rget(B0, j+1)*w0[5] +
        rget(C0, j-1)*w0[6] + rget(C0, j)*w0[7] + rget(C0, j+1)*w0[8];
      float a1 =
        rget(A1, j-1)*w1[0] + rget(A1, j)*w1[1] + rget(A1, j+1)*w1[2] +
        rget(B1, j-1)*w1[3] + rget(B1, j)*w1[4] + rget(B1, j+1)*w1[5] +
        rget(C1, j-1)*w1[6] + rget(C1, j)*w1[7] + rget(C1, j+1)*w1[8];
      unsigned pk = (unsigned)f2bf(a0) | ((unsigned)f2bf(a1) << 16);
      unsigned La = ((unsigned)cb << 12) + ((unsigned)(px0 + j) << 4) + ((unsigned)ep << 2);
      *(unsigned*)(yrow + swz(La)) = pk;
    }
  }

  // ---------------- GEMM phase ----------------
  int wave = t >> 6;
  int l = t & 63;
  int l15 = l & 15, lg = l >> 4;
  int coBase = (wave >> 1) * 64;
  int pxBase = (wave & 1) * 128;

  // A frags issued before the barrier to overlap their latency with it
  bf16x8 Af[4][4];
#pragma unroll
  for (int m = 0; m < 4; ++m)
#pragma unroll
    for (int kk = 0; kk < 4; ++kk)
      Af[m][kk] = *(const bf16x8*)(wb + (coBase + m * 16 + l15) * CIN + kk * 32 + lg * 8);

  __syncthreads();

  f32x4 acc[4][8];
#pragma unroll
  for (int m = 0; m < 4; ++m)
#pragma unroll
    for (int n = 0; n < 8; ++n) acc[m][n] = (f32x4){0.f, 0.f, 0.f, 0.f};

#pragma unroll
  for (int n = 0; n < 8; ++n) {
    bf16x8 Bf[4];
#pragma unroll
    for (int kk = 0; kk < 4; ++kk) {
      unsigned La = ((unsigned)(kk * 4 + lg) << 12) + ((unsigned)(pxBase + n * 16 + l15) << 4);
      Bf[kk] = *(const bf16x8*)(yrow + swz(La));
    }
#pragma unroll
    for (int m = 0; m < 4; ++m)
#pragma unroll
      for (int kk = 0; kk < 4; ++kk)
        acc[m][n] = __builtin_amdgcn_mfma_f32_16x16x32_bf16(Af[m][kk], Bf[kk], acc[m][n], 0, 0, 0);
  }

  float* ob = out + (size_t)b * COUT * HW + (size_t)h * W;
#pragma unroll
  for (int m = 0; m < 4; ++m)
#pragma unroll
    for (int n = 0; n < 8; ++n)
#pragma unroll
      for (int r = 0; r < 4; ++r) {
        int co = coBase + m * 16 + lg * 4 + r;
        int px = pxBase + n * 16 + l15;
        ob[(size_t)co * HW + px] = acc[m][n][r];
      }
}

extern "C" void kernel_launch(void* const* d_in, const int* in_sizes, int n_in,
                              void* d_out, int out_size, void* d_ws, size_t ws_size,
                              hipStream_t stream) {
  const float* x   = (const float*)d_in[0];
  const float* wdw = (const float*)d_in[1];
  const float* wpw = (const float*)d_in[2];
  float* out = (float*)d_out;

  unsigned short* wbb = (unsigned short*)d_ws;   // 64 KB bf16 weights

  cvt_wpw<<<(COUT * CIN + 255) / 256, 256, 0, stream>>>(wpw, wbb);
  fused_kernel<<<B * H, 512, 0, stream>>>(x, wdw, wbb, out);
}